// Round 8
// baseline (123.359 us; speedup 1.0000x reference)
//
#include <hip/hip_runtime.h>
#include <math.h>

#define N_NODES 100000
#define N_EDGES 1600000

#define BUCKETS 16
#define GSPLIT 16
#define BUCKET_NODES (N_NODES / BUCKETS)   // 6250 -> 25 KB LDS
#define NSEG (BUCKETS * GSPLIT)            // 256 segments
#define CAP 8192                           // mean ~6272/segment, >24 sigma slack
#define CPAD 32                            // ints per counter -> 128 B line each
#define EPB 512                            // edges per block in msg_part (2/thread)

typedef _Float16 half8 __attribute__((ext_vector_type(8)));
typedef _Float16 half4 __attribute__((ext_vector_type(4)));

__device__ __forceinline__ unsigned int pack_entry(int local, float m) {
    _Float16 h = (_Float16)m;
    unsigned short u;
    __builtin_memcpy(&u, &h, 2);
    return ((unsigned int)local << 16) | u;
}
__device__ __forceinline__ float entry_msg(unsigned int e) {
    unsigned short u = (unsigned short)(e & 0xFFFFu);
    _Float16 h;
    __builtin_memcpy(&h, &u, 2);
    return (float)h;
}

// ---------------------------------------------------------------------------
// fp16 packed gather tables (together 4.0 MB -> fit ONE per-XCD L2):
//   srcw[i] = 32 B: {pos.xyz, f0..f8, pad4}   posh[i] = 8 B: {pos.xyz, pad}
// Block 0 also zeroes the padded counters (saves a memset dispatch).
// ---------------------------------------------------------------------------
__global__ __launch_bounds__(256) void pack_kernel(
    const float* __restrict__ pos,
    const float* __restrict__ feats,
    half8* __restrict__ srcw,             // [N_NODES*2]
    half4* __restrict__ posh,             // [N_NODES]
    int*   __restrict__ counters)         // [NSEG*CPAD]
{
    const int i = blockIdx.x * blockDim.x + threadIdx.x;
    if (blockIdx.x == 0) {
        for (int c = threadIdx.x; c < NSEG * CPAD; c += 256) counters[c] = 0;
    }
    if (i >= N_NODES) return;
    const float* p = pos + 3 * i;
    const float* f = feats + 9 * i;
    half8 a, b;
    a[0] = (_Float16)p[0]; a[1] = (_Float16)p[1]; a[2] = (_Float16)p[2];
    a[3] = (_Float16)f[0]; a[4] = (_Float16)f[1]; a[5] = (_Float16)f[2];
    a[6] = (_Float16)f[3]; a[7] = (_Float16)f[4];
    b[0] = (_Float16)f[5]; b[1] = (_Float16)f[6]; b[2] = (_Float16)f[7];
    b[3] = (_Float16)f[8]; b[4] = (_Float16)0; b[5] = (_Float16)0;
    b[6] = (_Float16)0;    b[7] = (_Float16)0;
    srcw[2 * i + 0] = a;
    srcw[2 * i + 1] = b;
    half4 q;
    q[0] = (_Float16)p[0]; q[1] = (_Float16)p[1]; q[2] = (_Float16)p[2];
    q[3] = (_Float16)0;
    posh[i] = q;
}

__device__ __forceinline__ float edge_msg_h(
    const half8 ra, const half8 rb, const half4 pd,
    const float* __restrict__ sW1, const float* __restrict__ sW2)
{
    const float vx = (float)pd[0] - (float)ra[0];
    const float vy = (float)pd[1] - (float)ra[1];
    const float vz = (float)pd[2] - (float)ra[2];

    const float r   = sqrtf(vx * vx + vy * vy + vz * vz);
    const float inv = 1.0f / (r + 1e-12f);
    const float x = vx * inv, y = vy * inv, z = vz * inv;

    const float s3  = 1.7320508075688772f;
    const float s5  = 2.23606797749979f;
    const float s15 = 3.872983346207417f;
    const float sh1 = s3 * x;
    const float sh2 = s3 * y;
    const float sh3 = s3 * z;
    const float sh4 = s15 * x * z;
    const float sh5 = s15 * x * y;
    const float sh6 = s5 * (y * y - 0.5f * (x * x + z * z));
    const float sh7 = s15 * y * z;
    const float sh8 = 0.5f * s15 * (z * z - x * x);

    // radial basis: q = r*(11/5); active bins k-1, k
    const float q = r * 2.2f;
    const int   k = (int)floorf(q);
    int   b0 = k - 1, b1 = k;
    const float d0 = q - (float)k;
    const float d1 = d0 - 1.0f;
    const float A = 8.43357307f;              // 1.14136 * e^2
    float e0 = 0.0f, e1 = 0.0f;
    if (b0 >= 0 && b0 < 10) {
        const float dd = d0 * d0;
        if (dd < 1.0f) e0 = A * expf(-1.0f / (1.0f - dd));
    }
    if (b1 >= 0 && b1 < 10) {
        const float dd = d1 * d1;
        if (dd < 1.0f) e1 = A * expf(-1.0f / (1.0f - dd));
    }
    b0 = (b0 >= 0 && b0 < 10) ? b0 : 0;
    b1 = (b1 >= 0 && b1 < 10) ? b1 : 0;

    const float* w1r0 = sW1 + b0 * 17;
    const float* w1r1 = sW1 + b1 * 17;
    float acc0 = 0.0f, acc1 = 0.0f, acc2 = 0.0f;
#pragma unroll
    for (int j = 0; j < 16; ++j) {
        const float hj = fmaxf(e0 * w1r0[j] + e1 * w1r1[j], 0.0f);
        acc0 = fmaf(hj, sW2[j * 3 + 0], acc0);
        acc1 = fmaf(hj, sW2[j * 3 + 1], acc1);
        acc2 = fmaf(hj, sW2[j * 3 + 2], acc2);
    }

    const float path_s = (float)ra[3];
    const float path_p = ((float)ra[4] * sh1 + (float)ra[5] * sh2
                        + (float)ra[6] * sh3) * 0.5773502691896258f;
    const float path_d = ((float)ra[7] * sh4 + (float)rb[0] * sh5
                        + (float)rb[1] * sh6 + (float)rb[2] * sh7
                        + (float)rb[3] * sh8) * 0.4472135954999579f;

    const float FINAL = 0.06454972243679028f;  // sqrt(2)/(4*sqrt(3)*sqrt(10))
    return (acc0 * path_s + acc1 * path_p + acc2 * path_d) * FINAL;
}

// ---------------------------------------------------------------------------
// Phase 1 (fused): msg + radix-partition into BUCKETS x GSPLIT segments.
// 2 edges/thread (halved barrier count); per-thread LDS-atomic ranking
// (16-deep chains), 16 global atomics/block onto 128B-padded counters.
// Seg entries are 4B: (local<<16 | fp16 msg).
// ---------------------------------------------------------------------------
__global__ __launch_bounds__(256) void msg_part_kernel(
    const half8* __restrict__ srcw,
    const half4* __restrict__ posh,
    const float* __restrict__ W1,
    const float* __restrict__ W2,
    const int* __restrict__ edge_src,
    const int* __restrict__ edge_dst,
    int*  __restrict__ counters,          // [NSEG*CPAD], zeroed by pack_kernel
    unsigned int* __restrict__ segs)      // [NSEG][CAP]
{
    __shared__ float sW1[10 * 17];
    __shared__ float sW2[16 * 3];
    __shared__ int cnt[BUCKETS];
    __shared__ int basesm[BUCKETS];
    const int t = threadIdx.x;
    if (t < 160) sW1[(t >> 4) * 17 + (t & 15)] = W1[t];
    if (t < 48)  sW2[t] = W2[t];
    if (t < BUCKETS) cnt[t] = 0;
    __syncthreads();

    const int e0 = blockIdx.x * EPB + t;      // grid exact: 3125*512 == N_EDGES
    const int e1 = e0 + 256;

    const int s0 = edge_src[e0];
    const int d0 = edge_dst[e0];
    const int s1 = edge_src[e1];
    const int d1 = edge_dst[e1];

    const half8 ra0 = srcw[2 * s0 + 0];
    const half8 rb0 = srcw[2 * s0 + 1];
    const half4 pd0 = posh[d0];
    const half8 ra1 = srcw[2 * s1 + 0];
    const half8 rb1 = srcw[2 * s1 + 1];
    const half4 pd1 = posh[d1];

    const float m0 = edge_msg_h(ra0, rb0, pd0, sW1, sW2);
    const float m1 = edge_msg_h(ra1, rb1, pd1, sW1, sW2);

    const int bk0 = d0 / BUCKET_NODES;
    const int lo0 = d0 - bk0 * BUCKET_NODES;
    const int bk1 = d1 / BUCKET_NODES;
    const int lo1 = d1 - bk1 * BUCKET_NODES;

    const int rank0 = atomicAdd(&cnt[bk0], 1);
    const int rank1 = atomicAdd(&cnt[bk1], 1);
    __syncthreads();

    const int g = blockIdx.x & (GSPLIT - 1);
    if (t < BUCKETS)
        basesm[t] = atomicAdd(&counters[(t * GSPLIT + g) * CPAD], cnt[t]);
    __syncthreads();

    const int slot0 = basesm[bk0] + rank0;
    if (slot0 < CAP)
        segs[(size_t)(bk0 * GSPLIT + g) * CAP + slot0] = pack_entry(lo0, m0);
    const int slot1 = basesm[bk1] + rank1;
    if (slot1 < CAP)
        segs[(size_t)(bk1 * GSPLIT + g) * CAP + slot1] = pack_entry(lo1, m1);
}

// ---------------------------------------------------------------------------
// Phase 2: block = one segment; stream 4B entries (all lanes useful),
// dense ds_add_f32 into 25 KB LDS, coalesced slab write.
// ---------------------------------------------------------------------------
__global__ __launch_bounds__(256) void scatter_kernel(
    const int* __restrict__ counters,
    const unsigned int* __restrict__ segs,
    float* __restrict__ slabs)            // [NSEG][BUCKET_NODES]
{
    __shared__ float acc[BUCKET_NODES];
    const int seg = blockIdx.x;
    const int t = threadIdx.x;
    for (int i = t; i < BUCKET_NODES; i += 256) acc[i] = 0.0f;
    __syncthreads();

    int count = counters[seg * CPAD];
    if (count > CAP) count = CAP;
    const unsigned int* sp = segs + (size_t)seg * CAP;
    for (int i = t; i < count; i += 256) {
        const unsigned int pr = sp[i];
        atomicAdd(&acc[pr >> 16], entry_msg(pr));
    }
    __syncthreads();

    float* slab = slabs + (size_t)seg * BUCKET_NODES;
    for (int i = t; i < BUCKET_NODES; i += 256) slab[i] = acc[i];
}

// Phase 3: out[n] = sum over the GSPLIT slabs of n's bucket.
__global__ __launch_bounds__(256) void reduce_kernel(
    const float* __restrict__ slabs, float* __restrict__ out)
{
    const int n = blockIdx.x * blockDim.x + threadIdx.x;
    if (n >= N_NODES) return;
    const int b = n / BUCKET_NODES;
    const int i = n - b * BUCKET_NODES;
    const float* sl = slabs + ((size_t)b * GSPLIT) * BUCKET_NODES + i;
    float sum = 0.0f;
#pragma unroll
    for (int g = 0; g < GSPLIT; ++g) sum += sl[(size_t)g * BUCKET_NODES];
    out[n] = sum;
}

// Fallback (ws too small): direct atomic kernel.
__global__ __launch_bounds__(256) void edge_kernel_direct(
    const float* __restrict__ pos,
    const float* __restrict__ node_feats,
    const float* __restrict__ W1,
    const float* __restrict__ W2,
    const int*   __restrict__ edge_src,
    const int*   __restrict__ edge_dst,
    float* __restrict__ out)
{
    __shared__ float sW1[10 * 17];
    __shared__ float sW2[16 * 3];
    const int t = threadIdx.x;
    if (t < 160) sW1[(t >> 4) * 17 + (t & 15)] = W1[t];
    if (t < 48)  sW2[t] = W2[t];
    __syncthreads();

    const int e = blockIdx.x * blockDim.x + t;
    if (e >= N_EDGES) return;

    const int src = edge_src[e];
    const int dst = edge_dst[e];
    const float* ps = pos + 3 * src;
    const float* pdp = pos + 3 * dst;
    const float* xf = node_feats + 9 * src;
    half8 ra, rb; half4 pd;
    ra[0] = (_Float16)ps[0]; ra[1] = (_Float16)ps[1]; ra[2] = (_Float16)ps[2];
    ra[3] = (_Float16)xf[0]; ra[4] = (_Float16)xf[1]; ra[5] = (_Float16)xf[2];
    ra[6] = (_Float16)xf[3]; ra[7] = (_Float16)xf[4];
    rb[0] = (_Float16)xf[5]; rb[1] = (_Float16)xf[6]; rb[2] = (_Float16)xf[7];
    rb[3] = (_Float16)xf[8]; rb[4] = rb[5] = rb[6] = rb[7] = (_Float16)0;
    pd[0] = (_Float16)pdp[0]; pd[1] = (_Float16)pdp[1]; pd[2] = (_Float16)pdp[2];
    pd[3] = (_Float16)0;
    const float m = edge_msg_h(ra, rb, pd, sW1, sW2);
    unsafeAtomicAdd(out + dst, m);
}

extern "C" void kernel_launch(void* const* d_in, const int* in_sizes, int n_in,
                              void* d_out, int out_size, void* d_ws, size_t ws_size,
                              hipStream_t stream) {
    const float* pos        = (const float*)d_in[0];
    const float* node_feats = (const float*)d_in[1];
    const float* W1         = (const float*)d_in[2];
    const float* W2         = (const float*)d_in[3];
    const int*   edge_src   = (const int*)d_in[4];
    const int*   edge_dst   = (const int*)d_in[5];
    float* out = (float*)d_out;

    const size_t srcw_bytes = (size_t)N_NODES * 2 * sizeof(half8);            // 3.2 MB
    const size_t posh_bytes = (size_t)N_NODES * sizeof(half4);                // 0.8 MB
    const size_t cnt_bytes  = (size_t)NSEG * CPAD * sizeof(int);              // 32 KB
    const size_t seg_bytes  = (size_t)NSEG * CAP * sizeof(unsigned int);      // 8.4 MB
    const size_t slab_bytes = (size_t)NSEG * BUCKET_NODES * sizeof(float);    // 6.4 MB
    const size_t need = srcw_bytes + posh_bytes + cnt_bytes + seg_bytes + slab_bytes;

    if (ws_size >= need) {
        char* w = (char*)d_ws;
        half8* srcw  = (half8*)w;        w += srcw_bytes;
        half4* posh  = (half4*)w;        w += posh_bytes;
        int*   cnts  = (int*)w;          w += cnt_bytes;
        unsigned int* segs = (unsigned int*)w;  w += seg_bytes;
        float* slabs = (float*)w;

        pack_kernel<<<(N_NODES + 255) / 256, 256, 0, stream>>>(
            pos, node_feats, srcw, posh, cnts);
        msg_part_kernel<<<N_EDGES / EPB, 256, 0, stream>>>(
            srcw, posh, W1, W2, edge_src, edge_dst, cnts, segs);
        scatter_kernel<<<NSEG, 256, 0, stream>>>(cnts, segs, slabs);
        reduce_kernel<<<(N_NODES + 255) / 256, 256, 0, stream>>>(slabs, out);
    } else {
        hipMemsetAsync(out, 0, N_NODES * sizeof(float), stream);
        edge_kernel_direct<<<(N_EDGES + 255) / 256, 256, 0, stream>>>(
            pos, node_feats, W1, W2, edge_src, edge_dst, out);
    }
}

// Round 9
// 120.056 us; speedup vs baseline: 1.0275x; 1.0275x over previous
//
#include <hip/hip_runtime.h>
#include <math.h>

#define N_NODES 100000
#define N_EDGES 1600000

#define BUCKETS 16
#define GSPLIT 16
#define BUCKET_NODES (N_NODES / BUCKETS)   // 6250 -> 25 KB LDS in scatter
#define NSEG (BUCKETS * GSPLIT)            // 256 segments
#define CAP 8192                           // mean ~6272/segment, >24 sigma slack
#define CPAD 32                            // ints per counter -> 128 B line each
#define EPB 512                            // edges per block in msg_part (2/thread)

#define LUTN 1024                          // intervals over r in [0,5]
#define LUT_SCALE 204.8f                   // LUTN / 5.0

#define PACK_BLOCKS ((N_NODES + 255) / 256)        // 391
#define LUT_BLOCKS  ((LUTN + 1 + 255) / 256)       // 5

typedef _Float16 half8 __attribute__((ext_vector_type(8)));
typedef _Float16 half4 __attribute__((ext_vector_type(4)));

__device__ __forceinline__ unsigned int pack_entry(int local, float m) {
    _Float16 h = (_Float16)m;
    unsigned short u;
    __builtin_memcpy(&u, &h, 2);
    return ((unsigned int)local << 16) | u;
}
__device__ __forceinline__ float entry_msg(unsigned int e) {
    unsigned short u = (unsigned short)(e & 0xFFFFu);
    _Float16 h;
    __builtin_memcpy(&h, &u, 2);
    return (float)h;
}

// Exact radial weights w(r) = FINAL * (relu(emb(r)@W1) @ W2), fp32.
__device__ __forceinline__ float4 radial_w(float r, const float* W1, const float* W2) {
    const float q = r * 2.2f;
    const int   k = (int)floorf(q);
    int   b0 = k - 1, b1 = k;
    const float d0 = q - (float)k;
    const float d1 = d0 - 1.0f;
    const float A = 8.43357307f;              // 1.14136 * e^2
    float e0 = 0.0f, e1 = 0.0f;
    if (b0 >= 0 && b0 < 10) {
        const float dd = d0 * d0;
        if (dd < 1.0f) e0 = A * expf(-1.0f / (1.0f - dd));
    }
    if (b1 >= 0 && b1 < 10) {
        const float dd = d1 * d1;
        if (dd < 1.0f) e1 = A * expf(-1.0f / (1.0f - dd));
    }
    b0 = (b0 >= 0 && b0 < 10) ? b0 : 0;
    b1 = (b1 >= 0 && b1 < 10) ? b1 : 0;
    float acc0 = 0.0f, acc1 = 0.0f, acc2 = 0.0f;
#pragma unroll
    for (int j = 0; j < 16; ++j) {
        const float hj = fmaxf(e0 * W1[b0 * 16 + j] + e1 * W1[b1 * 16 + j], 0.0f);
        acc0 = fmaf(hj, W2[j * 3 + 0], acc0);
        acc1 = fmaf(hj, W2[j * 3 + 1], acc1);
        acc2 = fmaf(hj, W2[j * 3 + 2], acc2);
    }
    const float FINAL = 0.06454972243679028f;  // sqrt(2)/(4*sqrt(3)*sqrt(10))
    return make_float4(acc0 * FINAL, acc1 * FINAL, acc2 * FINAL, 0.0f);
}

// ---------------------------------------------------------------------------
// Fused prologue: blocks [0,391) pack fp16 tables (block 0 also zeroes the
// padded counters); blocks [391,396) build the 1025-entry radial LUT exactly.
//   srcw[i] = 32 B {pos.xyz, f0..f8, pad4}   posh[i] = 8 B {pos.xyz, pad}
// ---------------------------------------------------------------------------
__global__ __launch_bounds__(256) void pack_kernel(
    const float* __restrict__ pos,
    const float* __restrict__ feats,
    const float* __restrict__ W1,
    const float* __restrict__ W2,
    half8* __restrict__ srcw,             // [N_NODES*2]
    half4* __restrict__ posh,             // [N_NODES]
    int*   __restrict__ counters,         // [NSEG*CPAD]
    float4* __restrict__ lut)             // [LUTN+1]
{
    if (blockIdx.x >= PACK_BLOCKS) {
        const int i = (blockIdx.x - PACK_BLOCKS) * 256 + threadIdx.x;
        if (i <= LUTN) lut[i] = radial_w((float)i * (5.0f / (float)LUTN), W1, W2);
        return;
    }
    const int i = blockIdx.x * blockDim.x + threadIdx.x;
    if (blockIdx.x == 0) {
        for (int c = threadIdx.x; c < NSEG * CPAD; c += 256) counters[c] = 0;
    }
    if (i >= N_NODES) return;
    const float* p = pos + 3 * i;
    const float* f = feats + 9 * i;
    half8 a, b;
    a[0] = (_Float16)p[0]; a[1] = (_Float16)p[1]; a[2] = (_Float16)p[2];
    a[3] = (_Float16)f[0]; a[4] = (_Float16)f[1]; a[5] = (_Float16)f[2];
    a[6] = (_Float16)f[3]; a[7] = (_Float16)f[4];
    b[0] = (_Float16)f[5]; b[1] = (_Float16)f[6]; b[2] = (_Float16)f[7];
    b[3] = (_Float16)f[8]; b[4] = (_Float16)0; b[5] = (_Float16)0;
    b[6] = (_Float16)0;    b[7] = (_Float16)0;
    srcw[2 * i + 0] = a;
    srcw[2 * i + 1] = b;
    half4 qv;
    qv[0] = (_Float16)p[0]; qv[1] = (_Float16)p[1]; qv[2] = (_Float16)p[2];
    qv[3] = (_Float16)0;
    posh[i] = qv;
}

// Geometry + LUT-lerp message. sLUT is the LDS copy of the radial LUT.
__device__ __forceinline__ float edge_msg_lut(
    const half8 ra, const half8 rb, const half4 pd,
    const float4* __restrict__ sLUT)
{
    const float vx = (float)pd[0] - (float)ra[0];
    const float vy = (float)pd[1] - (float)ra[1];
    const float vz = (float)pd[2] - (float)ra[2];

    const float r   = sqrtf(vx * vx + vy * vy + vz * vz);
    const float inv = 1.0f / (r + 1e-12f);
    const float x = vx * inv, y = vy * inv, z = vz * inv;

    const float s3  = 1.7320508075688772f;
    const float s5  = 2.23606797749979f;
    const float s15 = 3.872983346207417f;
    const float sh1 = s3 * x;
    const float sh2 = s3 * y;
    const float sh3 = s3 * z;
    const float sh4 = s15 * x * z;
    const float sh5 = s15 * x * y;
    const float sh6 = s5 * (y * y - 0.5f * (x * x + z * z));
    const float sh7 = s15 * y * z;
    const float sh8 = 0.5f * s15 * (z * z - x * x);

    // radial weights via LUT lerp; node LUTN holds exact 0 (r>=5 -> w=0),
    // clamping i to LUTN-1 with fr>=1 extrapolates into the zero tail
    // (|w'| there ~1e-19 -> error negligible).
    float t = r * LUT_SCALE;
    int   i = (int)t;
    i = (i < LUTN) ? i : (LUTN - 1);
    const float fr = t - (float)i;
    const float4 wa = sLUT[i];
    const float4 wb = sLUT[i + 1];
    const float w0 = fmaf(fr, wb.x - wa.x, wa.x);
    const float w1 = fmaf(fr, wb.y - wa.y, wa.y);
    const float w2 = fmaf(fr, wb.z - wa.z, wa.z);

    const float path_s = (float)ra[3];
    const float path_p = ((float)ra[4] * sh1 + (float)ra[5] * sh2
                        + (float)ra[6] * sh3) * 0.5773502691896258f;
    const float path_d = ((float)ra[7] * sh4 + (float)rb[0] * sh5
                        + (float)rb[1] * sh6 + (float)rb[2] * sh7
                        + (float)rb[3] * sh8) * 0.4472135954999579f;

    return w0 * path_s + w1 * path_p + w2 * path_d;
}

// ---------------------------------------------------------------------------
// Phase 1 (fused): msg + radix-partition into BUCKETS x GSPLIT segments.
// LUT in LDS (16.4 KB) replaces the per-edge MLP (was ~80 ds_read + 2 expf
// + ~48 FMA per edge). 2 edges/thread; LDS-atomic ranking; 16 global
// atomics/block onto 128B-padded counters. Seg entries 4B (local<<16|fp16).
// ---------------------------------------------------------------------------
__global__ __launch_bounds__(256) void msg_part_kernel(
    const half8* __restrict__ srcw,
    const half4* __restrict__ posh,
    const float4* __restrict__ lut,
    const int* __restrict__ edge_src,
    const int* __restrict__ edge_dst,
    int*  __restrict__ counters,          // [NSEG*CPAD], zeroed by pack_kernel
    unsigned int* __restrict__ segs)      // [NSEG][CAP]
{
    __shared__ float4 sLUT[LUTN + 1];
    __shared__ int cnt[BUCKETS];
    __shared__ int basesm[BUCKETS];
    const int t = threadIdx.x;
    for (int i = t; i <= LUTN; i += 256) sLUT[i] = lut[i];
    if (t < BUCKETS) cnt[t] = 0;
    __syncthreads();

    const int e0 = blockIdx.x * EPB + t;      // grid exact: 3125*512 == N_EDGES
    const int e1 = e0 + 256;

    const int s0 = edge_src[e0];
    const int d0 = edge_dst[e0];
    const int s1 = edge_src[e1];
    const int d1 = edge_dst[e1];

    const half8 ra0 = srcw[2 * s0 + 0];
    const half8 rb0 = srcw[2 * s0 + 1];
    const half4 pd0 = posh[d0];
    const half8 ra1 = srcw[2 * s1 + 0];
    const half8 rb1 = srcw[2 * s1 + 1];
    const half4 pd1 = posh[d1];

    const float m0 = edge_msg_lut(ra0, rb0, pd0, sLUT);
    const float m1 = edge_msg_lut(ra1, rb1, pd1, sLUT);

    const int bk0 = d0 / BUCKET_NODES;
    const int lo0 = d0 - bk0 * BUCKET_NODES;
    const int bk1 = d1 / BUCKET_NODES;
    const int lo1 = d1 - bk1 * BUCKET_NODES;

    const int rank0 = atomicAdd(&cnt[bk0], 1);
    const int rank1 = atomicAdd(&cnt[bk1], 1);
    __syncthreads();

    const int g = blockIdx.x & (GSPLIT - 1);
    if (t < BUCKETS)
        basesm[t] = atomicAdd(&counters[(t * GSPLIT + g) * CPAD], cnt[t]);
    __syncthreads();

    const int slot0 = basesm[bk0] + rank0;
    if (slot0 < CAP)
        segs[(size_t)(bk0 * GSPLIT + g) * CAP + slot0] = pack_entry(lo0, m0);
    const int slot1 = basesm[bk1] + rank1;
    if (slot1 < CAP)
        segs[(size_t)(bk1 * GSPLIT + g) * CAP + slot1] = pack_entry(lo1, m1);
}

// ---------------------------------------------------------------------------
// Phase 2: block = one segment; stream 4B entries (all lanes useful),
// dense ds_add_f32 into 25 KB LDS, coalesced slab write.
// ---------------------------------------------------------------------------
__global__ __launch_bounds__(256) void scatter_kernel(
    const int* __restrict__ counters,
    const unsigned int* __restrict__ segs,
    float* __restrict__ slabs)            // [NSEG][BUCKET_NODES]
{
    __shared__ float acc[BUCKET_NODES];
    const int seg = blockIdx.x;
    const int t = threadIdx.x;
    for (int i = t; i < BUCKET_NODES; i += 256) acc[i] = 0.0f;
    __syncthreads();

    int count = counters[seg * CPAD];
    if (count > CAP) count = CAP;
    const unsigned int* sp = segs + (size_t)seg * CAP;
    for (int i = t; i < count; i += 256) {
        const unsigned int pr = sp[i];
        atomicAdd(&acc[pr >> 16], entry_msg(pr));
    }
    __syncthreads();

    float* slab = slabs + (size_t)seg * BUCKET_NODES;
    for (int i = t; i < BUCKET_NODES; i += 256) slab[i] = acc[i];
}

// Phase 3: out[n] = sum over the GSPLIT slabs of n's bucket.
__global__ __launch_bounds__(256) void reduce_kernel(
    const float* __restrict__ slabs, float* __restrict__ out)
{
    const int n = blockIdx.x * blockDim.x + threadIdx.x;
    if (n >= N_NODES) return;
    const int b = n / BUCKET_NODES;
    const int i = n - b * BUCKET_NODES;
    const float* sl = slabs + ((size_t)b * GSPLIT) * BUCKET_NODES + i;
    float sum = 0.0f;
#pragma unroll
    for (int g = 0; g < GSPLIT; ++g) sum += sl[(size_t)g * BUCKET_NODES];
    out[n] = sum;
}

// Fallback (ws too small): direct atomic kernel with exact per-edge math.
__global__ __launch_bounds__(256) void edge_kernel_direct(
    const float* __restrict__ pos,
    const float* __restrict__ node_feats,
    const float* __restrict__ W1,
    const float* __restrict__ W2,
    const int*   __restrict__ edge_src,
    const int*   __restrict__ edge_dst,
    float* __restrict__ out)
{
    const int e = blockIdx.x * blockDim.x + threadIdx.x;
    if (e >= N_EDGES) return;

    const int src = edge_src[e];
    const int dst = edge_dst[e];
    const float* ps = pos + 3 * src;
    const float* pdp = pos + 3 * dst;
    const float* xf = node_feats + 9 * src;

    const float vx = pdp[0] - ps[0];
    const float vy = pdp[1] - ps[1];
    const float vz = pdp[2] - ps[2];
    const float r   = sqrtf(vx * vx + vy * vy + vz * vz);
    const float inv = 1.0f / (r + 1e-12f);
    const float x = vx * inv, y = vy * inv, z = vz * inv;

    const float s3  = 1.7320508075688772f;
    const float s5  = 2.23606797749979f;
    const float s15 = 3.872983346207417f;
    const float4 w = radial_w(r, W1, W2);
    const float path_s = xf[0];
    const float path_p = (xf[1] * s3 * x + xf[2] * s3 * y + xf[3] * s3 * z)
                         * 0.5773502691896258f;
    const float path_d = (xf[4] * s15 * x * z + xf[5] * s15 * x * y
                        + xf[6] * s5 * (y * y - 0.5f * (x * x + z * z))
                        + xf[7] * s15 * y * z
                        + xf[8] * 0.5f * s15 * (z * z - x * x))
                         * 0.4472135954999579f;
    unsafeAtomicAdd(out + dst, w.x * path_s + w.y * path_p + w.z * path_d);
}

extern "C" void kernel_launch(void* const* d_in, const int* in_sizes, int n_in,
                              void* d_out, int out_size, void* d_ws, size_t ws_size,
                              hipStream_t stream) {
    const float* pos        = (const float*)d_in[0];
    const float* node_feats = (const float*)d_in[1];
    const float* W1         = (const float*)d_in[2];
    const float* W2         = (const float*)d_in[3];
    const int*   edge_src   = (const int*)d_in[4];
    const int*   edge_dst   = (const int*)d_in[5];
    float* out = (float*)d_out;

    const size_t srcw_bytes = (size_t)N_NODES * 2 * sizeof(half8);            // 3.2 MB
    const size_t posh_bytes = (size_t)N_NODES * sizeof(half4);                // 0.8 MB
    const size_t lut_bytes  = (size_t)(LUTN + 1) * sizeof(float4);            // 16.4 KB
    const size_t lut_pad    = (lut_bytes + 63) & ~(size_t)63;
    const size_t cnt_bytes  = (size_t)NSEG * CPAD * sizeof(int);              // 32 KB
    const size_t seg_bytes  = (size_t)NSEG * CAP * sizeof(unsigned int);      // 8.4 MB
    const size_t slab_bytes = (size_t)NSEG * BUCKET_NODES * sizeof(float);    // 6.4 MB
    const size_t need = srcw_bytes + posh_bytes + lut_pad + cnt_bytes
                      + seg_bytes + slab_bytes;

    if (ws_size >= need) {
        char* w = (char*)d_ws;
        half8*  srcw = (half8*)w;          w += srcw_bytes;
        half4*  posh = (half4*)w;          w += posh_bytes;
        float4* lut  = (float4*)w;         w += lut_pad;
        int*    cnts = (int*)w;            w += cnt_bytes;
        unsigned int* segs = (unsigned int*)w;  w += seg_bytes;
        float*  slabs = (float*)w;

        pack_kernel<<<PACK_BLOCKS + LUT_BLOCKS, 256, 0, stream>>>(
            pos, node_feats, W1, W2, srcw, posh, cnts, lut);
        msg_part_kernel<<<N_EDGES / EPB, 256, 0, stream>>>(
            srcw, posh, lut, edge_src, edge_dst, cnts, segs);
        scatter_kernel<<<NSEG, 256, 0, stream>>>(cnts, segs, slabs);
        reduce_kernel<<<(N_NODES + 255) / 256, 256, 0, stream>>>(slabs, out);
    } else {
        hipMemsetAsync(out, 0, N_NODES * sizeof(float), stream);
        edge_kernel_direct<<<(N_EDGES + 255) / 256, 256, 0, stream>>>(
            pos, node_feats, W1, W2, edge_src, edge_dst, out);
    }
}

// Round 10
// 114.640 us; speedup vs baseline: 1.0761x; 1.0472x over previous
//
#include <hip/hip_runtime.h>
#include <math.h>

#define N_NODES 100000
#define N_EDGES 1600000

#define BUCKETS 16
#define GSPLIT 16
#define BUCKET_NODES (N_NODES / BUCKETS)   // 6250 -> 25 KB LDS in scatter
#define NSEG (BUCKETS * GSPLIT)            // 256 segments
#define CAP 8192                           // mean ~6250/segment, >25 sigma slack
#define CPAD 32                            // ints per counter -> 128 B line each

#define LUTN 1024                          // intervals over r in [0,5]
#define LUT_SCALE 204.8f                   // LUTN / 5.0

#define PACK_BLOCKS ((N_NODES + 255) / 256)        // 391
#define LUT_BLOCKS  ((LUTN + 1 + 255) / 256)       // 5
#define NQ (N_EDGES / 4)                   // 400000 int4 groups
#define MSG_BLOCKS ((NQ + 255) / 256)      // 1563

typedef _Float16 half8 __attribute__((ext_vector_type(8)));

__device__ __forceinline__ unsigned int pack_entry(int local, float m) {
    _Float16 h = (_Float16)m;
    unsigned short u;
    __builtin_memcpy(&u, &h, 2);
    return ((unsigned int)local << 16) | u;
}
__device__ __forceinline__ float entry_msg(unsigned int e) {
    unsigned short u = (unsigned short)(e & 0xFFFFu);
    _Float16 h;
    __builtin_memcpy(&h, &u, 2);
    return (float)h;
}

// Exact radial weights w(r) = FINAL * (relu(emb(r)@W1) @ W2), fp32.
__device__ __forceinline__ float4 radial_w(float r, const float* W1, const float* W2) {
    const float q = r * 2.2f;
    const int   k = (int)floorf(q);
    int   b0 = k - 1, b1 = k;
    const float d0 = q - (float)k;
    const float d1 = d0 - 1.0f;
    const float A = 8.43357307f;              // 1.14136 * e^2
    float e0 = 0.0f, e1 = 0.0f;
    if (b0 >= 0 && b0 < 10) {
        const float dd = d0 * d0;
        if (dd < 1.0f) e0 = A * expf(-1.0f / (1.0f - dd));
    }
    if (b1 >= 0 && b1 < 10) {
        const float dd = d1 * d1;
        if (dd < 1.0f) e1 = A * expf(-1.0f / (1.0f - dd));
    }
    b0 = (b0 >= 0 && b0 < 10) ? b0 : 0;
    b1 = (b1 >= 0 && b1 < 10) ? b1 : 0;
    float acc0 = 0.0f, acc1 = 0.0f, acc2 = 0.0f;
#pragma unroll
    for (int j = 0; j < 16; ++j) {
        const float hj = fmaxf(e0 * W1[b0 * 16 + j] + e1 * W1[b1 * 16 + j], 0.0f);
        acc0 = fmaf(hj, W2[j * 3 + 0], acc0);
        acc1 = fmaf(hj, W2[j * 3 + 1], acc1);
        acc2 = fmaf(hj, W2[j * 3 + 2], acc2);
    }
    const float FINAL = 0.06454972243679028f;  // sqrt(2)/(4*sqrt(3)*sqrt(10))
    return make_float4(acc0 * FINAL, acc1 * FINAL, acc2 * FINAL, 0.0f);
}

// ---------------------------------------------------------------------------
// Fused prologue: blocks [0,391) pack the fp16 table (block 0 also zeroes the
// padded counters); blocks [391,396) build the 1025-entry radial LUT exactly.
//   srcw[i] = 32 B {pos.xyz, f0..f8, pad4}  — 3.2 MB, sole gather table
//   (dst position is read from srcw[2*d] too; no separate pos table).
// ---------------------------------------------------------------------------
__global__ __launch_bounds__(256) void pack_kernel(
    const float* __restrict__ pos,
    const float* __restrict__ feats,
    const float* __restrict__ W1,
    const float* __restrict__ W2,
    half8* __restrict__ srcw,             // [N_NODES*2]
    int*   __restrict__ counters,         // [NSEG*CPAD]
    float4* __restrict__ lut)             // [LUTN+1]
{
    if (blockIdx.x >= PACK_BLOCKS) {
        const int i = (blockIdx.x - PACK_BLOCKS) * 256 + threadIdx.x;
        if (i <= LUTN) lut[i] = radial_w((float)i * (5.0f / (float)LUTN), W1, W2);
        return;
    }
    const int i = blockIdx.x * blockDim.x + threadIdx.x;
    if (blockIdx.x == 0) {
        for (int c = threadIdx.x; c < NSEG * CPAD; c += 256) counters[c] = 0;
    }
    if (i >= N_NODES) return;
    const float* p = pos + 3 * i;
    const float* f = feats + 9 * i;
    half8 a, b;
    a[0] = (_Float16)p[0]; a[1] = (_Float16)p[1]; a[2] = (_Float16)p[2];
    a[3] = (_Float16)f[0]; a[4] = (_Float16)f[1]; a[5] = (_Float16)f[2];
    a[6] = (_Float16)f[3]; a[7] = (_Float16)f[4];
    b[0] = (_Float16)f[5]; b[1] = (_Float16)f[6]; b[2] = (_Float16)f[7];
    b[3] = (_Float16)f[8]; b[4] = (_Float16)0; b[5] = (_Float16)0;
    b[6] = (_Float16)0;    b[7] = (_Float16)0;
    srcw[2 * i + 0] = a;
    srcw[2 * i + 1] = b;
}

// Geometry + LUT-lerp message. pd = srcw row of the dst node (pos in [0..2]).
__device__ __forceinline__ float edge_msg_lut(
    const half8 ra, const half8 rb, const half8 pd,
    const float4* __restrict__ sLUT)
{
    const float vx = (float)pd[0] - (float)ra[0];
    const float vy = (float)pd[1] - (float)ra[1];
    const float vz = (float)pd[2] - (float)ra[2];

    const float r   = sqrtf(vx * vx + vy * vy + vz * vz);
    const float inv = 1.0f / (r + 1e-12f);
    const float x = vx * inv, y = vy * inv, z = vz * inv;

    const float s3  = 1.7320508075688772f;
    const float s5  = 2.23606797749979f;
    const float s15 = 3.872983346207417f;
    const float sh1 = s3 * x;
    const float sh2 = s3 * y;
    const float sh3 = s3 * z;
    const float sh4 = s15 * x * z;
    const float sh5 = s15 * x * y;
    const float sh6 = s5 * (y * y - 0.5f * (x * x + z * z));
    const float sh7 = s15 * y * z;
    const float sh8 = 0.5f * s15 * (z * z - x * x);

    // radial weights via LUT lerp; entry LUTN is exact 0 (r>=5 -> w=0).
    float t = r * LUT_SCALE;
    int   i = (int)t;
    i = (i < LUTN) ? i : (LUTN - 1);
    const float fr = t - (float)i;
    const float4 wa = sLUT[i];
    const float4 wb = sLUT[i + 1];
    const float w0 = fmaf(fr, wb.x - wa.x, wa.x);
    const float w1 = fmaf(fr, wb.y - wa.y, wa.y);
    const float w2 = fmaf(fr, wb.z - wa.z, wa.z);

    const float path_s = (float)ra[3];
    const float path_p = ((float)ra[4] * sh1 + (float)ra[5] * sh2
                        + (float)ra[6] * sh3) * 0.5773502691896258f;
    const float path_d = ((float)ra[7] * sh4 + (float)rb[0] * sh5
                        + (float)rb[1] * sh6 + (float)rb[2] * sh7
                        + (float)rb[3] * sh8) * 0.4472135954999579f;

    return w0 * path_s + w1 * path_p + w2 * path_d;
}

// ---------------------------------------------------------------------------
// Phase 1 (fused): msg + radix-partition. 4 consecutive edges/thread via int4
// index loads; 12 divergent gathers issued up-front (2x MLP vs round 9's 6).
// LDS-atomic ranking; 16 global atomics/block onto 128B-padded counters.
// ---------------------------------------------------------------------------
__global__ __launch_bounds__(256) void msg_part_kernel(
    const half8* __restrict__ srcw,
    const float4* __restrict__ lut,
    const int4* __restrict__ src4,        // [NQ]
    const int4* __restrict__ dst4,        // [NQ]
    int*  __restrict__ counters,          // [NSEG*CPAD], zeroed by pack_kernel
    unsigned int* __restrict__ segs)      // [NSEG][CAP]
{
    __shared__ float4 sLUT[LUTN + 1];
    __shared__ int cnt[BUCKETS];
    __shared__ int basesm[BUCKETS];
    const int t = threadIdx.x;
    for (int i = t; i <= LUTN; i += 256) sLUT[i] = lut[i];
    if (t < BUCKETS) cnt[t] = 0;
    __syncthreads();

    const int q = blockIdx.x * 256 + t;
    const bool valid = q < NQ;
    int4 s4 = make_int4(0, 0, 0, 0), d4 = make_int4(0, 0, 0, 0);
    if (valid) { s4 = src4[q]; d4 = dst4[q]; }
    const int si[4] = { s4.x, s4.y, s4.z, s4.w };
    const int di[4] = { d4.x, d4.y, d4.z, d4.w };

    // issue all 12 divergent gathers up front (single 3.2 MB L2-resident table)
    half8 ra[4], rb[4], pa[4];
#pragma unroll
    for (int i = 0; i < 4; ++i) {
        ra[i] = srcw[2 * si[i] + 0];
        rb[i] = srcw[2 * si[i] + 1];
        pa[i] = srcw[2 * di[i] + 0];
    }

    float m[4]; int bk[4], lo[4], rank[4];
#pragma unroll
    for (int i = 0; i < 4; ++i) {
        m[i]  = edge_msg_lut(ra[i], rb[i], pa[i], sLUT);
        bk[i] = di[i] / BUCKET_NODES;
        lo[i] = di[i] - bk[i] * BUCKET_NODES;
        rank[i] = valid ? atomicAdd(&cnt[bk[i]], 1) : 0;
    }
    __syncthreads();

    const int g = blockIdx.x & (GSPLIT - 1);
    if (t < BUCKETS)
        basesm[t] = atomicAdd(&counters[(t * GSPLIT + g) * CPAD], cnt[t]);
    __syncthreads();

    if (valid) {
#pragma unroll
        for (int i = 0; i < 4; ++i) {
            const int slot = basesm[bk[i]] + rank[i];
            if (slot < CAP)
                segs[(size_t)(bk[i] * GSPLIT + g) * CAP + slot] =
                    pack_entry(lo[i], m[i]);
        }
    }
}

// ---------------------------------------------------------------------------
// Phase 2: block = one segment; stream 4B entries (all lanes useful),
// dense ds_add_f32 into 25 KB LDS, coalesced slab write.
// ---------------------------------------------------------------------------
__global__ __launch_bounds__(256) void scatter_kernel(
    const int* __restrict__ counters,
    const unsigned int* __restrict__ segs,
    float* __restrict__ slabs)            // [NSEG][BUCKET_NODES]
{
    __shared__ float acc[BUCKET_NODES];
    const int seg = blockIdx.x;
    const int t = threadIdx.x;
    for (int i = t; i < BUCKET_NODES; i += 256) acc[i] = 0.0f;
    __syncthreads();

    int count = counters[seg * CPAD];
    if (count > CAP) count = CAP;
    const unsigned int* sp = segs + (size_t)seg * CAP;
    for (int i = t; i < count; i += 256) {
        const unsigned int pr = sp[i];
        atomicAdd(&acc[pr >> 16], entry_msg(pr));
    }
    __syncthreads();

    float* slab = slabs + (size_t)seg * BUCKET_NODES;
    for (int i = t; i < BUCKET_NODES; i += 256) slab[i] = acc[i];
}

// Phase 3: out[n] = sum over the GSPLIT slabs of n's bucket.
__global__ __launch_bounds__(256) void reduce_kernel(
    const float* __restrict__ slabs, float* __restrict__ out)
{
    const int n = blockIdx.x * blockDim.x + threadIdx.x;
    if (n >= N_NODES) return;
    const int b = n / BUCKET_NODES;
    const int i = n - b * BUCKET_NODES;
    const float* sl = slabs + ((size_t)b * GSPLIT) * BUCKET_NODES + i;
    float sum = 0.0f;
#pragma unroll
    for (int g = 0; g < GSPLIT; ++g) sum += sl[(size_t)g * BUCKET_NODES];
    out[n] = sum;
}

// Fallback (ws too small): direct atomic kernel with exact per-edge math.
__global__ __launch_bounds__(256) void edge_kernel_direct(
    const float* __restrict__ pos,
    const float* __restrict__ node_feats,
    const float* __restrict__ W1,
    const float* __restrict__ W2,
    const int*   __restrict__ edge_src,
    const int*   __restrict__ edge_dst,
    float* __restrict__ out)
{
    const int e = blockIdx.x * blockDim.x + threadIdx.x;
    if (e >= N_EDGES) return;

    const int src = edge_src[e];
    const int dst = edge_dst[e];
    const float* ps = pos + 3 * src;
    const float* pdp = pos + 3 * dst;
    const float* xf = node_feats + 9 * src;

    const float vx = pdp[0] - ps[0];
    const float vy = pdp[1] - ps[1];
    const float vz = pdp[2] - ps[2];
    const float r   = sqrtf(vx * vx + vy * vy + vz * vz);
    const float inv = 1.0f / (r + 1e-12f);
    const float x = vx * inv, y = vy * inv, z = vz * inv;

    const float s3  = 1.7320508075688772f;
    const float s5  = 2.23606797749979f;
    const float s15 = 3.872983346207417f;
    const float4 w = radial_w(r, W1, W2);
    const float path_s = xf[0];
    const float path_p = (xf[1] * s3 * x + xf[2] * s3 * y + xf[3] * s3 * z)
                         * 0.5773502691896258f;
    const float path_d = (xf[4] * s15 * x * z + xf[5] * s15 * x * y
                        + xf[6] * s5 * (y * y - 0.5f * (x * x + z * z))
                        + xf[7] * s15 * y * z
                        + xf[8] * 0.5f * s15 * (z * z - x * x))
                         * 0.4472135954999579f;
    unsafeAtomicAdd(out + dst, w.x * path_s + w.y * path_p + w.z * path_d);
}

extern "C" void kernel_launch(void* const* d_in, const int* in_sizes, int n_in,
                              void* d_out, int out_size, void* d_ws, size_t ws_size,
                              hipStream_t stream) {
    const float* pos        = (const float*)d_in[0];
    const float* node_feats = (const float*)d_in[1];
    const float* W1         = (const float*)d_in[2];
    const float* W2         = (const float*)d_in[3];
    const int*   edge_src   = (const int*)d_in[4];
    const int*   edge_dst   = (const int*)d_in[5];
    float* out = (float*)d_out;

    const size_t srcw_bytes = (size_t)N_NODES * 2 * sizeof(half8);            // 3.2 MB
    const size_t lut_bytes  = (size_t)(LUTN + 1) * sizeof(float4);            // 16.4 KB
    const size_t lut_pad    = (lut_bytes + 63) & ~(size_t)63;
    const size_t cnt_bytes  = (size_t)NSEG * CPAD * sizeof(int);              // 32 KB
    const size_t seg_bytes  = (size_t)NSEG * CAP * sizeof(unsigned int);      // 8.4 MB
    const size_t slab_bytes = (size_t)NSEG * BUCKET_NODES * sizeof(float);    // 6.4 MB
    const size_t need = srcw_bytes + lut_pad + cnt_bytes + seg_bytes + slab_bytes;

    if (ws_size >= need) {
        char* w = (char*)d_ws;
        half8*  srcw = (half8*)w;          w += srcw_bytes;
        float4* lut  = (float4*)w;         w += lut_pad;
        int*    cnts = (int*)w;            w += cnt_bytes;
        unsigned int* segs = (unsigned int*)w;  w += seg_bytes;
        float*  slabs = (float*)w;

        pack_kernel<<<PACK_BLOCKS + LUT_BLOCKS, 256, 0, stream>>>(
            pos, node_feats, W1, W2, srcw, cnts, lut);
        msg_part_kernel<<<MSG_BLOCKS, 256, 0, stream>>>(
            srcw, lut, (const int4*)edge_src, (const int4*)edge_dst, cnts, segs);
        scatter_kernel<<<NSEG, 256, 0, stream>>>(cnts, segs, slabs);
        reduce_kernel<<<(N_NODES + 255) / 256, 256, 0, stream>>>(slabs, out);
    } else {
        hipMemsetAsync(out, 0, N_NODES * sizeof(float), stream);
        edge_kernel_direct<<<(N_EDGES + 255) / 256, 256, 0, stream>>>(
            pos, node_feats, W1, W2, edge_src, edge_dst, out);
    }
}